// Round 3
// baseline (3565.570 us; speedup 1.0000x reference)
//
#include <hip/hip_runtime.h>
#include <hip/hip_bf16.h>
#include <cstdint>

#define Bb 64
#define Cc 64
#define Tt 2048
#define Hh 128

__device__ __forceinline__ float fsig(float x)  { return 1.0f / (1.0f + __expf(-x)); }
__device__ __forceinline__ float ftanh(float x) { return 1.0f - 2.0f / (__expf(2.0f * x) + 1.0f); }

// ---------------- Kernel 1: fused bidirectional LSTM ----------------
// grid 128 = (dir*64 + b), block 512.
// lane l = gi*8 + kg: kg owns k-slice [16kg,16kg+16) of h, [8kg,8kg+8) of x.
// wave w owns output j in [16w, 16w+16); 8 row-passes/step:
//   row(p) = (p&3)*128 + 16w + (p>>2)*8 + gi   (p&3 = gate q: i,f,g,o)
// Partials reduced over kg via shfl_xor(1,2,4). One barrier/step (h dbuf).
__global__ __launch_bounds__(512) void lstm_kernel(
    const float* __restrict__ x,
    const float* __restrict__ Wih_f, const float* __restrict__ Whh_f,
    const float* __restrict__ bih_f, const float* __restrict__ bhh_f,
    const float* __restrict__ Wih_b, const float* __restrict__ Whh_b,
    const float* __restrict__ bih_b, const float* __restrict__ bhh_b,
    __hip_bfloat16* __restrict__ y)
{
    const int blk = blockIdx.x;
    const int dir = blk >> 6;
    const int b   = blk & 63;
    const int tid = threadIdx.x;
    const int w   = tid >> 6;     // wave id 0..7
    const int l   = tid & 63;
    const int gi  = l >> 3;       // 0..7
    const int kg  = l & 7;        // 0..7

    const float* Wih = dir ? Wih_b : Wih_f;
    const float* Whh = dir ? Whh_b : Whh_f;
    const float* bih = dir ? bih_b : bih_f;
    const float* bhh = dir ? bhh_b : bhh_f;

    // per-thread weights (full unroll -> registers)
    float wh[8][16];
    float wx[8][8];
    float bs[8];
    #pragma unroll
    for (int p = 0; p < 8; ++p) {
        const int row = ((p & 3) << 7) + (w << 4) + ((p >> 2) << 3) + gi;
        const float* wp = Whh + row * 128 + kg * 16;
        float4 a0 = *(const float4*)(wp + 0);
        float4 a1 = *(const float4*)(wp + 4);
        float4 a2 = *(const float4*)(wp + 8);
        float4 a3 = *(const float4*)(wp + 12);
        wh[p][0]=a0.x;  wh[p][1]=a0.y;  wh[p][2]=a0.z;  wh[p][3]=a0.w;
        wh[p][4]=a1.x;  wh[p][5]=a1.y;  wh[p][6]=a1.z;  wh[p][7]=a1.w;
        wh[p][8]=a2.x;  wh[p][9]=a2.y;  wh[p][10]=a2.z; wh[p][11]=a2.w;
        wh[p][12]=a3.x; wh[p][13]=a3.y; wh[p][14]=a3.z; wh[p][15]=a3.w;
        const float* xp = Wih + row * 64 + kg * 8;
        float4 b0 = *(const float4*)(xp + 0);
        float4 b1 = *(const float4*)(xp + 4);
        wx[p][0]=b0.x; wx[p][1]=b0.y; wx[p][2]=b0.z; wx[p][3]=b0.w;
        wx[p][4]=b1.x; wx[p][5]=b1.y; wx[p][6]=b1.z; wx[p][7]=b1.w;
        bs[p] = bih[row] + bhh[row];
    }

    __shared__ __align__(16) float xs[64 * 68];     // [tt][c], stride 68
    __shared__ __align__(16) float hsb[2][160];     // 8 groups * 20 (16 used + 4 pad)

    if (tid < 160) hsb[0][tid] = 0.0f;
    float c1 = 0.0f, c2 = 0.0f;
    const bool act = (kg == 0);

    for (int tile = 0; tile < 32; ++tile) {
        const int s0   = tile << 6;
        const int t_lo = dir ? (Tt - 64 - s0) : s0;
        // stage x[b][:, t_lo..t_lo+63] -> xs[tt][c] (coalesced along t)
        #pragma unroll
        for (int r = 0; r < 2; ++r) {
            int idx = (r << 9) + tid;          // 0..1023
            int c = idx >> 4, q = idx & 15;
            float4 v = *(const float4*)(x + ((size_t)b * Cc + c) * Tt + t_lo + (q << 2));
            xs[(q*4+0)*68 + c] = v.x;
            xs[(q*4+1)*68 + c] = v.y;
            xs[(q*4+2)*68 + c] = v.z;
            xs[(q*4+3)*68 + c] = v.w;
        }
        __syncthreads();

        for (int ss = 0; ss < 64; ++ss) {
            const int s  = s0 + ss;
            const int t  = dir ? (Tt - 1 - s) : s;
            const int tt = dir ? (63 - ss) : ss;

            const float* hr = hsb[s & 1];
            float4 h0 = *(const float4*)(hr + kg * 20 + 0);
            float4 h1 = *(const float4*)(hr + kg * 20 + 4);
            float4 h2 = *(const float4*)(hr + kg * 20 + 8);
            float4 h3 = *(const float4*)(hr + kg * 20 + 12);
            float4 xv0 = *(const float4*)(&xs[tt * 68 + kg * 8]);
            float4 xv1 = *(const float4*)(&xs[tt * 68 + kg * 8 + 4]);

            float zp[8];
            #pragma unroll
            for (int p = 0; p < 8; ++p) {
                float ax = 0.0f, ay = 0.0f;
                ax = fmaf(wh[p][0],  h0.x, ax);  ay = fmaf(wh[p][1],  h0.y, ay);
                ax = fmaf(wh[p][2],  h0.z, ax);  ay = fmaf(wh[p][3],  h0.w, ay);
                ax = fmaf(wh[p][4],  h1.x, ax);  ay = fmaf(wh[p][5],  h1.y, ay);
                ax = fmaf(wh[p][6],  h1.z, ax);  ay = fmaf(wh[p][7],  h1.w, ay);
                ax = fmaf(wh[p][8],  h2.x, ax);  ay = fmaf(wh[p][9],  h2.y, ay);
                ax = fmaf(wh[p][10], h2.z, ax);  ay = fmaf(wh[p][11], h2.w, ay);
                ax = fmaf(wh[p][12], h3.x, ax);  ay = fmaf(wh[p][13], h3.y, ay);
                ax = fmaf(wh[p][14], h3.z, ax);  ay = fmaf(wh[p][15], h3.w, ay);
                ax = fmaf(wx[p][0], xv0.x, ax);  ay = fmaf(wx[p][1], xv0.y, ay);
                ax = fmaf(wx[p][2], xv0.z, ax);  ay = fmaf(wx[p][3], xv0.w, ay);
                ax = fmaf(wx[p][4], xv1.x, ax);  ay = fmaf(wx[p][5], xv1.y, ay);
                ax = fmaf(wx[p][6], xv1.z, ax);  ay = fmaf(wx[p][7], xv1.w, ay);
                float sres = ax + ay;
                sres += __shfl_xor(sres, 1, 64);
                sres += __shfl_xor(sres, 2, 64);
                sres += __shfl_xor(sres, 4, 64);
                zp[p] = sres + bs[p];
            }

            if (act) {
                float zi = zp[0], zf = zp[1], zg = zp[2], zo = zp[3];
                c1 = fsig(zf) * c1 + fsig(zi) * ftanh(zg);
                float hh1 = fsig(zo) * ftanh(c1);
                zi = zp[4]; zf = zp[5]; zg = zp[6]; zo = zp[7];
                c2 = fsig(zf) * c2 + fsig(zi) * ftanh(zg);
                float hh2 = fsig(zo) * ftanh(c2);
                float* hw = hsb[(s + 1) & 1];
                hw[w * 20 + gi]     = hh1;
                hw[w * 20 + 8 + gi] = hh2;
                __hip_bfloat16* yp = y + ((size_t)b * Tt + t) * 256 + dir * 128 + (w << 4) + gi;
                yp[0] = __float2bfloat16(hh1);
                yp[8] = __float2bfloat16(hh2);
            }
            __syncthreads();
        }
    }
}

// ---------------- Kernel 2: attention scores ----------------
__global__ __launch_bounds__(256) void attn_scores_kernel(
    const __hip_bfloat16* __restrict__ y,
    const float* __restrict__ Wa, const float* __restrict__ ba,
    const float* __restrict__ Wu, const float* __restrict__ bu,
    float* __restrict__ scores)
{
    const int b  = blockIdx.y;
    const int t0 = blockIdx.x * 32;
    const int g  = threadIdx.x;

    __shared__ float ylds[32 * 256];
    __shared__ float red[32][4];

    const unsigned short* yb = (const unsigned short*)y + ((size_t)b * Tt + t0) * 256;
    #pragma unroll
    for (int r = 0; r < 4; ++r) {
        int base = (r * 256 + g) * 8;
        uint4 v = *(const uint4*)(yb + base);
        ylds[base+0] = __uint_as_float(v.x << 16);
        ylds[base+1] = __uint_as_float(v.x & 0xffff0000u);
        ylds[base+2] = __uint_as_float(v.y << 16);
        ylds[base+3] = __uint_as_float(v.y & 0xffff0000u);
        ylds[base+4] = __uint_as_float(v.z << 16);
        ylds[base+5] = __uint_as_float(v.z & 0xffff0000u);
        ylds[base+6] = __uint_as_float(v.w << 16);
        ylds[base+7] = __uint_as_float(v.w & 0xffff0000u);
    }
    __syncthreads();

    float uacc[32];
    #pragma unroll
    for (int t = 0; t < 32; ++t) uacc[t] = 0.0f;

    const float4* wa4 = (const float4*)(Wa + (size_t)g * 256);
    for (int k0 = 0; k0 < 64; ++k0) {
        float4 wv = wa4[k0];
        #pragma unroll
        for (int t = 0; t < 32; ++t) {
            float4 v = *(const float4*)(&ylds[t * 256 + k0 * 4]);
            uacc[t] += wv.x*v.x + wv.y*v.y + wv.z*v.z + wv.w*v.w;
        }
    }

    const float bag = ba[g];
    const float wug = Wu[g];
    const int lane = g & 63, wid = g >> 6;
    #pragma unroll
    for (int t = 0; t < 32; ++t) {
        float val = wug * ftanh(uacc[t] + bag);
        #pragma unroll
        for (int off = 32; off >= 1; off >>= 1)
            val += __shfl_down(val, off, 64);
        if (lane == 0) red[t][wid] = val;
    }
    __syncthreads();
    if (g < 32) {
        float s = red[g][0] + red[g][1] + red[g][2] + red[g][3] + bu[0];
        scores[(size_t)b * Tt + t0 + g] = s;
    }
}

// ---------------- Kernel 3: softmax + weighted sum ----------------
__global__ __launch_bounds__(256) void attn_out_kernel(
    const __hip_bfloat16* __restrict__ y,
    const float* __restrict__ scores,
    float* __restrict__ out)
{
    const int b = blockIdx.x;
    const int tid = threadIdx.x;
    const int lane = tid & 63, wid = tid >> 6;
    __shared__ float wls[2048];
    __shared__ float red[4];

    float m = -1e30f;
    for (int t = tid; t < Tt; t += 256) m = fmaxf(m, scores[(size_t)b*Tt + t]);
    #pragma unroll
    for (int off = 32; off >= 1; off >>= 1) m = fmaxf(m, __shfl_xor(m, off, 64));
    if (lane == 0) red[wid] = m;
    __syncthreads();
    m = fmaxf(fmaxf(red[0], red[1]), fmaxf(red[2], red[3]));
    __syncthreads();

    float sum = 0.0f;
    for (int t = tid; t < Tt; t += 256) {
        float e = __expf(scores[(size_t)b*Tt + t] - m);
        wls[t] = e;
        sum += e;
    }
    #pragma unroll
    for (int off = 32; off >= 1; off >>= 1) sum += __shfl_xor(sum, off, 64);
    if (lane == 0) red[wid] = sum;
    __syncthreads();
    const float inv = 1.0f / (red[0] + red[1] + red[2] + red[3]);

    const unsigned short* yb = (const unsigned short*)y + (size_t)b * Tt * 256 + tid;
    float acc = 0.0f;
    for (int t = 0; t < Tt; ++t) {
        acc += wls[t] * __uint_as_float(((unsigned)yb[(size_t)t * 256]) << 16);
    }
    out[b * 256 + tid] = acc * inv;
}

extern "C" void kernel_launch(void* const* d_in, const int* in_sizes, int n_in,
                              void* d_out, int out_size, void* d_ws, size_t ws_size,
                              hipStream_t stream) {
    const float* x     = (const float*)d_in[0];
    const float* Wih_f = (const float*)d_in[1];
    const float* Whh_f = (const float*)d_in[2];
    const float* bih_f = (const float*)d_in[3];
    const float* bhh_f = (const float*)d_in[4];
    const float* Wih_b = (const float*)d_in[5];
    const float* Whh_b = (const float*)d_in[6];
    const float* bih_b = (const float*)d_in[7];
    const float* bhh_b = (const float*)d_in[8];
    const float* Wa    = (const float*)d_in[9];
    const float* ba    = (const float*)d_in[10];
    const float* Wu    = (const float*)d_in[11];
    const float* bu    = (const float*)d_in[12];
    float* out = (float*)d_out;

    __hip_bfloat16* y = (__hip_bfloat16*)d_ws;
    float* scores = (float*)((char*)d_ws + (size_t)Bb * Tt * 256 * sizeof(__hip_bfloat16));

    hipLaunchKernelGGL(lstm_kernel, dim3(128), dim3(512), 0, stream,
                       x, Wih_f, Whh_f, bih_f, bhh_f, Wih_b, Whh_b, bih_b, bhh_b, y);
    hipLaunchKernelGGL(attn_scores_kernel, dim3(Tt / 32, Bb), dim3(256), 0, stream,
                       y, Wa, ba, Wu, bu, scores);
    hipLaunchKernelGGL(attn_out_kernel, dim3(Bb), dim3(256), 0, stream, y, scores, out);
}

// Round 5
// 2430.220 us; speedup vs baseline: 1.4672x; 1.4672x over previous
//
#include <hip/hip_runtime.h>
#include <hip/hip_bf16.h>
#include <cstdint>

#define Bb 64
#define Cc 64
#define Tt 2048
#define Hh 128

typedef __fp16 h2 __attribute__((ext_vector_type(2)));

union Pack4 { uint4 u; h2 h[4]; };

__device__ __forceinline__ float fsig(float x)  { return 1.0f / (1.0f + __expf(-x)); }
__device__ __forceinline__ float ftanh(float x) { return 1.0f - 2.0f / (__expf(2.0f * x) + 1.0f); }

// quad_perm DPP cross-lane add: CTRL=0xB1 -> lane^1, 0x4E -> lane^2
template<int CTRL>
__device__ __forceinline__ float dpp_add(float v) {
    int r = __builtin_amdgcn_update_dpp(0, __float_as_int(v), CTRL, 0xF, 0xF, true);
    return v + __int_as_float(r);
}

// ---------------- Kernel 1: fused bidirectional LSTM ----------------
// grid 128 = (dir*64 + b), block 512 (8 waves).
// lane l: kg = l&3 owns k-slice [32kg,32kg+32) of h and [16kg,16kg+16) of x;
//         gi = l>>2 (0..15). Wave w owns output j in [16w,16w+16).
// 4 passes p = gate (i,f,g,o): row = p*128 + 16w + gi.
// Weights f16-packed in registers (96 VGPRs + 4 bias). Partials reduced over
// kg via quad_perm DPP (xor1, xor2). One barrier/step, h double-buffered.
__global__ __launch_bounds__(512, 2) void lstm_kernel(
    const float* __restrict__ x,
    const float* __restrict__ Wih_f, const float* __restrict__ Whh_f,
    const float* __restrict__ bih_f, const float* __restrict__ bhh_f,
    const float* __restrict__ Wih_b, const float* __restrict__ Whh_b,
    const float* __restrict__ bih_b, const float* __restrict__ bhh_b,
    __hip_bfloat16* __restrict__ y)
{
    const int blk = blockIdx.x;
    const int dir = blk >> 6;
    const int b   = blk & 63;
    const int tid = threadIdx.x;
    const int w   = tid >> 6;     // wave 0..7
    const int l   = tid & 63;
    const int gi  = l >> 2;       // 0..15
    const int kg  = l & 3;        // 0..3

    const float* Wih = dir ? Wih_b : Wih_f;
    const float* Whh = dir ? Whh_b : Whh_f;
    const float* bih = dir ? bih_b : bih_f;
    const float* bhh = dir ? bhh_b : bhh_f;

    // f16-packed per-thread weights
    h2 wh2[4][16];
    h2 wx2[4][8];
    float bs4[4];
    #pragma unroll
    for (int p = 0; p < 4; ++p) {
        const int row = (p << 7) + (w << 4) + gi;
        const float* wp = Whh + row * 128 + kg * 32;
        #pragma unroll
        for (int r = 0; r < 8; ++r) {
            float4 v = *(const float4*)(wp + r * 4);
            wh2[p][r*2+0] = __builtin_amdgcn_cvt_pkrtz(v.x, v.y);
            wh2[p][r*2+1] = __builtin_amdgcn_cvt_pkrtz(v.z, v.w);
        }
        const float* xw = Wih + row * 64 + kg * 16;
        #pragma unroll
        for (int r = 0; r < 4; ++r) {
            float4 v = *(const float4*)(xw + r * 4);
            wx2[p][r*2+0] = __builtin_amdgcn_cvt_pkrtz(v.x, v.y);
            wx2[p][r*2+1] = __builtin_amdgcn_cvt_pkrtz(v.z, v.w);
        }
        bs4[p] = bih[row] + bhh[row];
    }

    __shared__ __align__(16) unsigned int xs16[64 * 32];   // [tt][c-pair], f16x2
    __shared__ __align__(16) __fp16 hbuf[2][128];          // double-buffered h (f16)

    if (tid < 64) ((unsigned int*)hbuf)[tid] = 0u;         // zero hbuf[0]
    float cst = 0.0f;
    const bool act = (kg == 0);

    for (int tile = 0; tile < 32; ++tile) {
        const int s0   = tile << 6;
        const int t_lo = dir ? (Tt - 64 - s0) : s0;
        // stage x[b][:, t_lo..t_lo+63] -> xs16[tt][c'] (f16x2, pairs (2c',2c'+1))
        {
            const int cp = tid >> 4;          // c-pair 0..31
            const int q  = tid & 15;          // 4 t's per thread
            const float* rA = x + ((size_t)b * Cc + 2 * cp) * Tt + t_lo + (q << 2);
            float4 va = *(const float4*)rA;
            float4 vb = *(const float4*)(rA + Tt);
            const float* pa = (const float*)&va;
            const float* pb = (const float*)&vb;
            #pragma unroll
            for (int j = 0; j < 4; ++j) {
                h2 pk = __builtin_amdgcn_cvt_pkrtz(pa[j], pb[j]);
                xs16[((q << 2) + j) * 32 + cp] = *(const unsigned int*)&pk;
            }
        }
        __syncthreads();

        for (int ss = 0; ss < 64; ++ss) {
            const int s  = s0 + ss;
            const int t  = dir ? (Tt - 1 - s) : s;
            const int tt = dir ? (63 - ss) : ss;
            const int cur = s & 1, nxt = cur ^ 1;

            const uint4* hp = (const uint4*)(&hbuf[cur][kg * 32]);
            Pack4 H0, H1, H2, H3;
            H0.u = hp[0]; H1.u = hp[1]; H2.u = hp[2]; H3.u = hp[3];
            const uint4* xp = (const uint4*)(&xs16[tt * 32 + (kg << 3)]);
            Pack4 X0, X1;
            X0.u = xp[0]; X1.u = xp[1];

            float zp[4];
            #pragma unroll
            for (int p = 0; p < 4; ++p) {
                float a0 = 0.0f, a1 = 0.0f;
                a0 = __builtin_amdgcn_fdot2(wh2[p][0],  H0.h[0], a0, false);
                a1 = __builtin_amdgcn_fdot2(wh2[p][1],  H0.h[1], a1, false);
                a0 = __builtin_amdgcn_fdot2(wh2[p][2],  H0.h[2], a0, false);
                a1 = __builtin_amdgcn_fdot2(wh2[p][3],  H0.h[3], a1, false);
                a0 = __builtin_amdgcn_fdot2(wh2[p][4],  H1.h[0], a0, false);
                a1 = __builtin_amdgcn_fdot2(wh2[p][5],  H1.h[1], a1, false);
                a0 = __builtin_amdgcn_fdot2(wh2[p][6],  H1.h[2], a0, false);
                a1 = __builtin_amdgcn_fdot2(wh2[p][7],  H1.h[3], a1, false);
                a0 = __builtin_amdgcn_fdot2(wh2[p][8],  H2.h[0], a0, false);
                a1 = __builtin_amdgcn_fdot2(wh2[p][9],  H2.h[1], a1, false);
                a0 = __builtin_amdgcn_fdot2(wh2[p][10], H2.h[2], a0, false);
                a1 = __builtin_amdgcn_fdot2(wh2[p][11], H2.h[3], a1, false);
                a0 = __builtin_amdgcn_fdot2(wh2[p][12], H3.h[0], a0, false);
                a1 = __builtin_amdgcn_fdot2(wh2[p][13], H3.h[1], a1, false);
                a0 = __builtin_amdgcn_fdot2(wh2[p][14], H3.h[2], a0, false);
                a1 = __builtin_amdgcn_fdot2(wh2[p][15], H3.h[3], a1, false);
                a0 = __builtin_amdgcn_fdot2(wx2[p][0],  X0.h[0], a0, false);
                a1 = __builtin_amdgcn_fdot2(wx2[p][1],  X0.h[1], a1, false);
                a0 = __builtin_amdgcn_fdot2(wx2[p][2],  X0.h[2], a0, false);
                a1 = __builtin_amdgcn_fdot2(wx2[p][3],  X0.h[3], a1, false);
                a0 = __builtin_amdgcn_fdot2(wx2[p][4],  X1.h[0], a0, false);
                a1 = __builtin_amdgcn_fdot2(wx2[p][5],  X1.h[1], a1, false);
                a0 = __builtin_amdgcn_fdot2(wx2[p][6],  X1.h[2], a0, false);
                a1 = __builtin_amdgcn_fdot2(wx2[p][7],  X1.h[3], a1, false);
                float sres = a0 + a1;
                sres = dpp_add<0xB1>(sres);   // + lane^1
                sres = dpp_add<0x4E>(sres);   // + lane^2
                zp[p] = sres + bs4[p];
            }

            if (act) {
                cst = fsig(zp[1]) * cst + fsig(zp[0]) * ftanh(zp[2]);
                float hh = fsig(zp[3]) * ftanh(cst);
                hbuf[nxt][(w << 4) + gi] = (__fp16)hh;
                y[((size_t)b * Tt + t) * 256 + dir * 128 + (w << 4) + gi] =
                    __float2bfloat16(hh);
            }
            __syncthreads();
        }
    }
}

// ---------------- Kernel 2: attention scores ----------------
__global__ __launch_bounds__(256) void attn_scores_kernel(
    const __hip_bfloat16* __restrict__ y,
    const float* __restrict__ Wa, const float* __restrict__ ba,
    const float* __restrict__ Wu, const float* __restrict__ bu,
    float* __restrict__ scores)
{
    const int b  = blockIdx.y;
    const int t0 = blockIdx.x * 32;
    const int g  = threadIdx.x;

    __shared__ float ylds[32 * 256];
    __shared__ float red[32][4];

    const unsigned short* yb = (const unsigned short*)y + ((size_t)b * Tt + t0) * 256;
    #pragma unroll
    for (int r = 0; r < 4; ++r) {
        int base = (r * 256 + g) * 8;
        uint4 v = *(const uint4*)(yb + base);
        ylds[base+0] = __uint_as_float(v.x << 16);
        ylds[base+1] = __uint_as_float(v.x & 0xffff0000u);
        ylds[base+2] = __uint_as_float(v.y << 16);
        ylds[base+3] = __uint_as_float(v.y & 0xffff0000u);
        ylds[base+4] = __uint_as_float(v.z << 16);
        ylds[base+5] = __uint_as_float(v.z & 0xffff0000u);
        ylds[base+6] = __uint_as_float(v.w << 16);
        ylds[base+7] = __uint_as_float(v.w & 0xffff0000u);
    }
    __syncthreads();

    float uacc[32];
    #pragma unroll
    for (int t = 0; t < 32; ++t) uacc[t] = 0.0f;

    const float4* wa4 = (const float4*)(Wa + (size_t)g * 256);
    for (int k0 = 0; k0 < 64; ++k0) {
        float4 wv = wa4[k0];
        #pragma unroll
        for (int t = 0; t < 32; ++t) {
            float4 v = *(const float4*)(&ylds[t * 256 + k0 * 4]);
            uacc[t] += wv.x*v.x + wv.y*v.y + wv.z*v.z + wv.w*v.w;
        }
    }

    const float bag = ba[g];
    const float wug = Wu[g];
    const int lane = g & 63, wid = g >> 6;
    #pragma unroll
    for (int t = 0; t < 32; ++t) {
        float val = wug * ftanh(uacc[t] + bag);
        #pragma unroll
        for (int off = 32; off >= 1; off >>= 1)
            val += __shfl_down(val, off, 64);
        if (lane == 0) red[t][wid] = val;
    }
    __syncthreads();
    if (g < 32) {
        float s = red[g][0] + red[g][1] + red[g][2] + red[g][3] + bu[0];
        scores[(size_t)b * Tt + t0 + g] = s;
    }
}

// ---------------- Kernel 3: softmax + weighted sum ----------------
__global__ __launch_bounds__(256) void attn_out_kernel(
    const __hip_bfloat16* __restrict__ y,
    const float* __restrict__ scores,
    float* __restrict__ out)
{
    const int b = blockIdx.x;
    const int tid = threadIdx.x;
    const int lane = tid & 63, wid = tid >> 6;
    __shared__ float wls[2048];
    __shared__ float red[4];

    float m = -1e30f;
    for (int t = tid; t < Tt; t += 256) m = fmaxf(m, scores[(size_t)b*Tt + t]);
    #pragma unroll
    for (int off = 32; off >= 1; off >>= 1) m = fmaxf(m, __shfl_xor(m, off, 64));
    if (lane == 0) red[wid] = m;
    __syncthreads();
    m = fmaxf(fmaxf(red[0], red[1]), fmaxf(red[2], red[3]));
    __syncthreads();

    float sum = 0.0f;
    for (int t = tid; t < Tt; t += 256) {
        float e = __expf(scores[(size_t)b*Tt + t] - m);
        wls[t] = e;
        sum += e;
    }
    #pragma unroll
    for (int off = 32; off >= 1; off >>= 1) sum += __shfl_xor(sum, off, 64);
    if (lane == 0) red[wid] = sum;
    __syncthreads();
    const float inv = 1.0f / (red[0] + red[1] + red[2] + red[3]);

    const unsigned short* yb = (const unsigned short*)y + (size_t)b * Tt * 256 + tid;
    float acc = 0.0f;
    for (int t = 0; t < Tt; ++t) {
        acc += wls[t] * __uint_as_float(((unsigned)yb[(size_t)t * 256]) << 16);
    }
    out[b * 256 + tid] = acc * inv;
}

extern "C" void kernel_launch(void* const* d_in, const int* in_sizes, int n_in,
                              void* d_out, int out_size, void* d_ws, size_t ws_size,
                              hipStream_t stream) {
    const float* x     = (const float*)d_in[0];
    const float* Wih_f = (const float*)d_in[1];
    const float* Whh_f = (const float*)d_in[2];
    const float* bih_f = (const float*)d_in[3];
    const float* bhh_f = (const float*)d_in[4];
    const float* Wih_b = (const float*)d_in[5];
    const float* Whh_b = (const float*)d_in[6];
    const float* bih_b = (const float*)d_in[7];
    const float* bhh_b = (const float*)d_in[8];
    const float* Wa    = (const float*)d_in[9];
    const float* ba    = (const float*)d_in[10];
    const float* Wu    = (const float*)d_in[11];
    const float* bu    = (const float*)d_in[12];
    float* out = (float*)d_out;

    __hip_bfloat16* y = (__hip_bfloat16*)d_ws;
    float* scores = (float*)((char*)d_ws + (size_t)Bb * Tt * 256 * sizeof(__hip_bfloat16));

    hipLaunchKernelGGL(lstm_kernel, dim3(128), dim3(512), 0, stream,
                       x, Wih_f, Whh_f, bih_f, bhh_f, Wih_b, Whh_b, bih_b, bhh_b, y);
    hipLaunchKernelGGL(attn_scores_kernel, dim3(Tt / 32, Bb), dim3(256), 0, stream,
                       y, Wa, ba, Wu, bu, scores);
    hipLaunchKernelGGL(attn_out_kernel, dim3(Bb), dim3(256), 0, stream, y, scores, out);
}